// Round 1
// baseline (195.936 us; speedup 1.0000x reference)
//
#include <hip/hip_runtime.h>

// Problem constants (from reference)
#define BATCH   4096
#define NLAB    16384
#define HID     1024
#define REC_PEN 1e-6

// Grid split: blocks [0, NB_BCE) stream BCE; blocks [NB_BCE, NB_BCE+NB_REC) do edges.
#define NB_BCE 2048
#define NB_REC 512
#define BLK    256

__device__ __forceinline__ float softplus_f(float x) {
    // logaddexp(0, x) = max(x,0) + log1p(exp(-|x|)), numerically stable
    return fmaxf(x, 0.0f) + log1pf(__expf(-fabsf(x)));
}

// Block-level f32 sum reduction; result valid on threadIdx.x == 0.
__device__ __forceinline__ float block_reduce_f32(float v) {
    #pragma unroll
    for (int off = 32; off > 0; off >>= 1)
        v += __shfl_down(v, off, 64);
    __shared__ float s[BLK / 64];
    const int wave = threadIdx.x >> 6;
    const int lane = threadIdx.x & 63;
    if (lane == 0) s[wave] = v;
    __syncthreads();
    float r = 0.0f;
    if (threadIdx.x == 0) {
        #pragma unroll
        for (int i = 0; i < BLK / 64; ++i) r += s[i];
    }
    return r;
}

// Fused partial-sum kernel.
//  blockIdx.x <  NB_BCE : grid-stride float4 over logits/targets -> partial[b]
//  blockIdx.x >= NB_BCE : one wave per edge (grid-stride), gather two rows of W
__global__ __launch_bounds__(BLK) void partials_kernel(
        const float4* __restrict__ x4,     // logits as float4
        const float4* __restrict__ y4,     // targets as float4
        const float4* __restrict__ w4,     // recursive_params as float4
        const int*    __restrict__ par,
        const int*    __restrict__ chi,
        float* __restrict__ partial,       // [NB_BCE + NB_REC]
        int n4, int nedges) {
    float acc = 0.0f;
    if (blockIdx.x < NB_BCE) {
        const int idx    = blockIdx.x * BLK + threadIdx.x;
        const int stride = NB_BCE * BLK;
        for (int i = idx; i < n4; i += stride) {
            float4 x = x4[i];
            float4 y = y4[i];
            acc += softplus_f(x.x) - x.x * y.x;
            acc += softplus_f(x.y) - x.y * y.y;
            acc += softplus_f(x.z) - x.z * y.z;
            acc += softplus_f(x.w) - x.w * y.w;
        }
    } else {
        const int bid    = blockIdx.x - NB_BCE;
        const int lane   = threadIdx.x & 63;
        const int waveId = (bid * BLK + threadIdx.x) >> 6;
        const int nwaves = (NB_REC * BLK) >> 6;
        for (int e = waveId; e < nedges; e += nwaves) {
            const float4* pr = w4 + (long)par[e] * (HID / 4);
            const float4* cr = w4 + (long)chi[e] * (HID / 4);
            #pragma unroll
            for (int k = 0; k < HID / 256; ++k) {   // 1024/4 floats4 per row / 64 lanes = 4
                float4 a = pr[lane + 64 * k];
                float4 b = cr[lane + 64 * k];
                float dx = a.x - b.x, dy = a.y - b.y;
                float dz = a.z - b.z, dw = a.w - b.w;
                acc += dx * dx + dy * dy + dz * dz + dw * dw;
            }
        }
    }
    float r = block_reduce_f32(acc);
    if (threadIdx.x == 0) partial[blockIdx.x] = r;
}

// Single-block final reduce in f64 (deterministic, no atomics).
__global__ __launch_bounds__(BLK) void final_reduce_kernel(
        const float* __restrict__ partial, float* __restrict__ out) {
    double a = 0.0, b = 0.0;
    for (int i = threadIdx.x; i < NB_BCE; i += BLK) a += (double)partial[i];
    for (int i = threadIdx.x; i < NB_REC; i += BLK) b += (double)partial[NB_BCE + i];
    __shared__ double sa[BLK], sb[BLK];
    sa[threadIdx.x] = a;
    sb[threadIdx.x] = b;
    __syncthreads();
    for (int off = BLK / 2; off > 0; off >>= 1) {
        if (threadIdx.x < off) {
            sa[threadIdx.x] += sa[threadIdx.x + off];
            sb[threadIdx.x] += sb[threadIdx.x + off];
        }
        __syncthreads();
    }
    if (threadIdx.x == 0) {
        double bce = sa[0] / ((double)BATCH * (double)NLAB);
        double reg = REC_PEN * 0.5 * sb[0];
        out[0] = (float)(bce + reg);
    }
}

extern "C" void kernel_launch(void* const* d_in, const int* in_sizes, int n_in,
                              void* d_out, int out_size, void* d_ws, size_t ws_size,
                              hipStream_t stream) {
    const float* logits  = (const float*)d_in[0];
    const float* targets = (const float*)d_in[1];
    const float* wparams = (const float*)d_in[2];
    const int*   par     = (const int*)d_in[3];
    const int*   chi     = (const int*)d_in[4];

    const int n  = in_sizes[0];      // BATCH*NLAB = 67,108,864
    const int n4 = n / 4;
    const int ne = in_sizes[3];      // 16383

    float* partial = (float*)d_ws;   // (NB_BCE + NB_REC) * 4 bytes

    partials_kernel<<<NB_BCE + NB_REC, BLK, 0, stream>>>(
        (const float4*)logits, (const float4*)targets, (const float4*)wparams,
        par, chi, partial, n4, ne);

    final_reduce_kernel<<<1, BLK, 0, stream>>>(partial, (float*)d_out);
}

// Round 2
// 122.358 us; speedup vs baseline: 1.6013x; 1.6013x over previous
//
#include <hip/hip_runtime.h>

// Problem constants (from reference)
#define BATCH   4096
#define NLAB    16384
#define HID     1024
#define REC_PEN 1e-6

// Grid split: blocks [0, NB_BCE) stream BCE; blocks [NB_BCE, NB_BCE+NB_REC) do edges.
#define NB_BCE 2048
#define NB_REC 512
#define BLK    256

__device__ __forceinline__ float softplus_f(float x) {
    // logaddexp(0, x) = max(x,0) + log(1 + exp(-|x|))
    // Hardware transcendentals (v_exp_f32 / v_log_f32): ~1 ulp each, plenty
    // for a mean over 67M elements vs 1.6e-2 absmax threshold.
    float e = __expf(-fabsf(x));
    return fmaxf(x, 0.0f) + __logf(1.0f + e);
}

// Block-level f32 sum reduction; result valid on threadIdx.x == 0.
__device__ __forceinline__ float block_reduce_f32(float v) {
    #pragma unroll
    for (int off = 32; off > 0; off >>= 1)
        v += __shfl_down(v, off, 64);
    __shared__ float s[BLK / 64];
    const int wave = threadIdx.x >> 6;
    const int lane = threadIdx.x & 63;
    if (lane == 0) s[wave] = v;
    __syncthreads();
    float r = 0.0f;
    if (threadIdx.x == 0) {
        #pragma unroll
        for (int i = 0; i < BLK / 64; ++i) r += s[i];
    }
    return r;
}

// Fused partial-sum kernel.
//  blockIdx.x <  NB_BCE : grid-stride float4 over logits/targets -> partial[b]
//  blockIdx.x >= NB_BCE : one wave per edge (grid-stride), gather two rows of W
__global__ __launch_bounds__(BLK) void partials_kernel(
        const float4* __restrict__ x4,     // logits as float4
        const float4* __restrict__ y4,     // targets as float4
        const float4* __restrict__ w4,     // recursive_params as float4
        const int*    __restrict__ par,
        const int*    __restrict__ chi,
        float* __restrict__ partial,       // [NB_BCE + NB_REC]
        int n4, int nedges) {
    float acc = 0.0f;
    if (blockIdx.x < NB_BCE) {
        const int idx    = blockIdx.x * BLK + threadIdx.x;
        const int stride = NB_BCE * BLK;
        for (int i = idx; i < n4; i += stride) {
            float4 x = x4[i];
            float4 y = y4[i];
            acc += softplus_f(x.x) - x.x * y.x;
            acc += softplus_f(x.y) - x.y * y.y;
            acc += softplus_f(x.z) - x.z * y.z;
            acc += softplus_f(x.w) - x.w * y.w;
        }
    } else {
        const int bid    = blockIdx.x - NB_BCE;
        const int lane   = threadIdx.x & 63;
        const int waveId = (bid * BLK + threadIdx.x) >> 6;
        const int nwaves = (NB_REC * BLK) >> 6;
        for (int e = waveId; e < nedges; e += nwaves) {
            const float4* pr = w4 + (long)par[e] * (HID / 4);
            const float4* cr = w4 + (long)chi[e] * (HID / 4);
            #pragma unroll
            for (int k = 0; k < HID / 256; ++k) {   // 256 float4/row / 64 lanes = 4
                float4 a = pr[lane + 64 * k];
                float4 b = cr[lane + 64 * k];
                float dx = a.x - b.x, dy = a.y - b.y;
                float dz = a.z - b.z, dw = a.w - b.w;
                acc += dx * dx + dy * dy + dz * dz + dw * dw;
            }
        }
    }
    float r = block_reduce_f32(acc);
    if (threadIdx.x == 0) partial[blockIdx.x] = r;
}

// Single-block final reduce in f64 (deterministic, no atomics).
__global__ __launch_bounds__(BLK) void final_reduce_kernel(
        const float* __restrict__ partial, float* __restrict__ out) {
    double a = 0.0, b = 0.0;
    for (int i = threadIdx.x; i < NB_BCE; i += BLK) a += (double)partial[i];
    for (int i = threadIdx.x; i < NB_REC; i += BLK) b += (double)partial[NB_BCE + i];
    __shared__ double sa[BLK], sb[BLK];
    sa[threadIdx.x] = a;
    sb[threadIdx.x] = b;
    __syncthreads();
    for (int off = BLK / 2; off > 0; off >>= 1) {
        if (threadIdx.x < off) {
            sa[threadIdx.x] += sa[threadIdx.x + off];
            sb[threadIdx.x] += sb[threadIdx.x + off];
        }
        __syncthreads();
    }
    if (threadIdx.x == 0) {
        double bce = sa[0] / ((double)BATCH * (double)NLAB);
        double reg = REC_PEN * 0.5 * sb[0];
        out[0] = (float)(bce + reg);
    }
}

extern "C" void kernel_launch(void* const* d_in, const int* in_sizes, int n_in,
                              void* d_out, int out_size, void* d_ws, size_t ws_size,
                              hipStream_t stream) {
    const float* logits  = (const float*)d_in[0];
    const float* targets = (const float*)d_in[1];
    const float* wparams = (const float*)d_in[2];
    const int*   par     = (const int*)d_in[3];
    const int*   chi     = (const int*)d_in[4];

    const int n  = in_sizes[0];      // BATCH*NLAB = 67,108,864
    const int n4 = n / 4;
    const int ne = in_sizes[3];      // 16383

    float* partial = (float*)d_ws;   // (NB_BCE + NB_REC) * 4 bytes

    partials_kernel<<<NB_BCE + NB_REC, BLK, 0, stream>>>(
        (const float4*)logits, (const float4*)targets, (const float4*)wparams,
        par, chi, partial, n4, ne);

    final_reduce_kernel<<<1, BLK, 0, stream>>>(partial, (float*)d_out);
}